// Round 8
// baseline (460.593 us; speedup 1.0000x reference)
//
#include <hip/hip_runtime.h>
#include <hip/hip_bf16.h>
#include <cstdint>
#include <cstddef>

// Problem constants (T,B,D,H,L = 1024,64,512,512,2)
#define T_DIM 1024
#define B_DIM 64
#define D_DIM 512
#define H_DIM 512
#define TBROWS (T_DIM * B_DIM)           // 65536 GEMM rows
#define BH (B_DIM * H_DIM)               // 32768
#define TBH ((size_t)T_DIM * (size_t)BH) // 33554432 elements

typedef __bf16 bf16x8 __attribute__((ext_vector_type(8)));
typedef float floatx4 __attribute__((ext_vector_type(4)));

// ---------------------------------------------------------------------------
// async global->LDS, 16B per lane. LDS dest is wave-uniform base + lane*16.
// ---------------------------------------------------------------------------
__device__ __forceinline__ void async_load16(const void* g, void* l) {
  __builtin_amdgcn_global_load_lds(
      (const __attribute__((address_space(1))) unsigned int*)g,
      (__attribute__((address_space(3))) unsigned int*)l,
      16, 0, 0);
}

// counted vmcnt wait (compile-time literal via switch)
__device__ __forceinline__ void wait_vm(int n) {
  switch (n) {
    case 2:  asm volatile("s_waitcnt vmcnt(2)"  ::: "memory"); break;
    case 4:  asm volatile("s_waitcnt vmcnt(4)"  ::: "memory"); break;
    case 5:  asm volatile("s_waitcnt vmcnt(5)"  ::: "memory"); break;
    case 6:  asm volatile("s_waitcnt vmcnt(6)"  ::: "memory"); break;
    case 8:  asm volatile("s_waitcnt vmcnt(8)"  ::: "memory"); break;
    case 9:  asm volatile("s_waitcnt vmcnt(9)"  ::: "memory"); break;
    case 12: asm volatile("s_waitcnt vmcnt(12)" ::: "memory"); break;
    case 16: asm volatile("s_waitcnt vmcnt(16)" ::: "memory"); break;
    case 24: asm volatile("s_waitcnt vmcnt(24)" ::: "memory"); break;
    case 32: asm volatile("s_waitcnt vmcnt(32)" ::: "memory"); break;
    case 40: asm volatile("s_waitcnt vmcnt(40)" ::: "memory"); break;
    case 48: asm volatile("s_waitcnt vmcnt(48)" ::: "memory"); break;
    default: asm volatile("s_waitcnt vmcnt(0)"  ::: "memory"); break;
  }
}

__device__ __forceinline__ int xcd_swizzle(int bid, int nwg) {
  // nwg % 8 == 0 for all launches here -> simple bijective form (m157/m204)
  return (bid & 7) * (nwg >> 3) + (bid >> 3);
}

// ---------------------------------------------------------------------------
// Merged prep:
//   blocks [0,128):    Wc[h,d] = sum_e w0[h,e]*fc_w[e,d] (bf16), 8 h-rows/blk
//   blocks [128,256):  w1 -> bf16
//   blocks [256,258):  bcomb[h] = b0[h] + sum_e w0[h,e]*fc_b[e]
// ---------------------------------------------------------------------------
__global__ __launch_bounds__(256) void prep_kernel(
    const float* __restrict__ w0, const float* __restrict__ fc_w,
    const float* __restrict__ fc_b, const float* __restrict__ b0,
    const float* __restrict__ w1, __bf16* __restrict__ Wc,
    __bf16* __restrict__ w1bf, float* __restrict__ bcomb) {
  const int blk = blockIdx.x;
  const int tid = threadIdx.x;
  if (blk < 128) {
    const int h0 = (blk >> 1) * 8;
    const int d = ((blk & 1) << 8) + tid;
    float a[8];
#pragma unroll
    for (int j = 0; j < 8; j++) a[j] = 0.f;
#pragma unroll 4
    for (int e = 0; e < D_DIM; ++e) {
      const float fv = fc_w[(size_t)e * D_DIM + d];
#pragma unroll
      for (int j = 0; j < 8; j++)
        a[j] = fmaf(w0[(size_t)(h0 + j) * D_DIM + e], fv, a[j]);  // w0: s_load
    }
#pragma unroll
    for (int j = 0; j < 8; j++)
      Wc[(size_t)(h0 + j) * D_DIM + d] = (__bf16)a[j];
  } else if (blk < 256) {
    const long i = ((long)(blk - 128) * 256 + tid) * 8;
    const float4 a = *(const float4*)(w1 + i);
    const float4 b = *(const float4*)(w1 + i + 4);
    bf16x8 v;
    v[0] = (__bf16)a.x; v[1] = (__bf16)a.y; v[2] = (__bf16)a.z; v[3] = (__bf16)a.w;
    v[4] = (__bf16)b.x; v[5] = (__bf16)b.y; v[6] = (__bf16)b.z; v[7] = (__bf16)b.w;
    *(bf16x8*)(w1bf + i) = v;
  } else {
    const int h = (blk - 256) * 256 + tid;
    float acc = b0[h];
    const float4* w4 = (const float4*)(w0 + (size_t)h * D_DIM);
#pragma unroll 4
    for (int e = 0; e < D_DIM / 4; ++e) {
      const float4 wv = w4[e];
      acc = fmaf(wv.x, fc_b[e * 4 + 0], acc);
      acc = fmaf(wv.y, fc_b[e * 4 + 1], acc);
      acc = fmaf(wv.z, fc_b[e * 4 + 2], acc);
      acc = fmaf(wv.w, fc_b[e * 4 + 3], acc);
    }
    bcomb[h] = acc;
  }
}

// ---------------------------------------------------------------------------
// GEMM0: A is f32 (raw x), 256x256 tile, BK=32, 16 waves (4M x 4N -> 64x64
// per wave), counted-vmcnt ring-4 planes, T14 reg-staged A with cvt-at-stage:
//   - A loaded f32 -> regs (2 x dwordx4/wave/phase, depth 2), converted to
//     bf16 ONCE, ds_write_b128 into bf16 planes with the gemm1-verified
//     layout (physical slot p holds global slot p ^ ((row>>1)&3)).
//   - B staged via global_load_lds (1/wave/phase, depth 3), same swizzle.
// Phase f: {issue A(f+2) regs + B(f+3) gload; asm wait_vm(9) [B(f) certified;
// steady, never 0]; valid s_barrier; ds_read frags + 16 MFMA (setprio);
// cvt+ds_write A(f+1); lgkmcnt(0); free s_barrier}. The compiler's dataflow
// waitcnt (vmcnt(4)) gates the A-reg consumption without draining prefetch.
// Phase loop FULLY UNROLLED (K hardcoded 512) -> static reg sets (rule #20)
// and exact waitcnt insertion. LDS 128 KB; 16 waves/CU (2x prior occupancy).
// ---------------------------------------------------------------------------
__global__ __launch_bounds__(1024, 1) void gemm_a32_rs(
    const float* __restrict__ A,    // [M,512] f32
    const __bf16* __restrict__ Bm,  // [N,512] bf16
    const float* __restrict__ bias, // [N]
    __bf16* __restrict__ C,         // [M,N] bf16
    int M, int N, int Kdummy) {
  (void)Kdummy;
  constexpr int K = 512;
  constexpr int F = K / 32;  // 16 phases
  __shared__ __bf16 As[4][256 * 32];  // 64 KB bf16 planes (ring-4)
  __shared__ __bf16 Bs[4][256 * 32];  // 64 KB

  const int tid = threadIdx.x;
  const int lane = tid & 63;
  const int wave = tid >> 6;          // 0..15
  const int wg = xcd_swizzle((int)blockIdx.x, (int)gridDim.x);
  const int nb = N / 256;
  const int bm = wg / nb;
  const int bn = wg % nb;
  const int m0 = bm * 256, n0 = bn * 256;

  floatx4 zero = {0.f, 0.f, 0.f, 0.f};
  floatx4 acc[4][4];
#pragma unroll
  for (int i = 0; i < 4; i++)
#pragma unroll
    for (int j = 0; j < 4; j++) acc[i][j] = zero;

  const int tm = (wave >> 2) * 64;    // 0..192
  const int tn = (wave & 3) * 64;     // 0..192
  const int lrow = lane & 15;
  const int sB = lane >> 4;           // 16B-slot 0..3 within a 64B row

  // A reg-staging map: wave owns plane rows [wave*16, wave*16+16)
  const int arow = wave * 16 + (lane >> 2);     // 0..255
  const int ap = lane & 3;                      // physical slot
  const int ag = ap ^ ((arow >> 1) & 3);        // global slot (involution)
  const float* Aw = A + (size_t)(m0 + arow) * K + ag * 8;

  // B staging map: wave owns plane rows [wave*16, wave*16+16) as well
  const int br = wave * 16 + (lane >> 2);
  const int bg = (lane & 3) ^ ((br >> 1) & 3);
  const __bf16* Bw = Bm + (size_t)(n0 + br) * K + bg * 8;

  float4 rA0[2], rA1[2];  // two static A-reg sets (depth 2)

  auto loadA = [&](float4* s, int p) {
    const float* gp = Aw + p * 32;
    s[0] = *(const float4*)(gp);
    s[1] = *(const float4*)(gp + 4);
  };
  auto writeA = [&](float4* s, int p) {
    bf16x8 v;
    v[0] = (__bf16)s[0].x; v[1] = (__bf16)s[0].y;
    v[2] = (__bf16)s[0].z; v[3] = (__bf16)s[0].w;
    v[4] = (__bf16)s[1].x; v[5] = (__bf16)s[1].y;
    v[6] = (__bf16)s[1].z; v[7] = (__bf16)s[1].w;
    *(bf16x8*)&As[p & 3][arow * 32 + ap * 8] = v;
  };
  auto issueB = [&](int p) {
    async_load16(Bw + (size_t)p * 32, &Bs[p & 3][wave * 512]);
  };
  // per-top in-flight count (A issues while g<=F-3, B while g<=F-4)
  auto kc = [&](int g) { return g <= F - 4 ? 3 : (g == F - 3 ? 2 : 0); };

  // prologue, shaped as steady pseudo-tops: B(0) | A(0),B(1) | A(1),B(2)
  issueB(0);
  loadA(rA0, 0); issueB(1);
  loadA(rA1, 1); issueB(2);
  writeA(rA0, 0);                               // compiler gates with vmcnt
  asm volatile("s_waitcnt lgkmcnt(0)" ::: "memory");
  __builtin_amdgcn_sched_barrier(0);

  auto phase = [&](int f, float4* Ls, float4* Ws) {
    // top: issue next stages (targets freed at f-1's free-barrier)
    __builtin_amdgcn_sched_barrier(0);
    if (f + 2 < F) loadA(Ls, f + 2);
    if (f + 3 < F) issueB(f + 3);
    __builtin_amdgcn_sched_barrier(0);
    wait_vm(kc(f - 2) + kc(f - 1) + kc(f));     // 9 steady; tail 8,5,2
    __builtin_amdgcn_sched_barrier(0);
    __builtin_amdgcn_s_barrier();               // plane f valid block-wide
    __builtin_amdgcn_sched_barrier(0);

    const int sl = f & 3;
    bf16x8 af[4], bfr[4];
#pragma unroll
    for (int i = 0; i < 4; i++) {
      const int ra = tm + i * 16 + lrow;
      af[i] = *(const bf16x8*)&As[sl][ra * 32 + ((sB ^ ((ra >> 1) & 3)) << 3)];
      const int rb = tn + i * 16 + lrow;
      bfr[i] = *(const bf16x8*)&Bs[sl][rb * 32 + ((sB ^ ((rb >> 1) & 3)) << 3)];
    }
    __builtin_amdgcn_s_setprio(1);
#pragma unroll
    for (int i = 0; i < 4; i++)
#pragma unroll
      for (int j = 0; j < 4; j++)
        acc[i][j] = __builtin_amdgcn_mfma_f32_16x16x32_bf16(af[i], bfr[j],
                                                            acc[i][j], 0, 0, 0);
    __builtin_amdgcn_s_setprio(0);
    __builtin_amdgcn_sched_barrier(0);
    // publish A(f+1) (slot freed at f-3's free-barrier; loads from f-1 top)
    if (f + 1 < F) writeA(Ws, f + 1);
    asm volatile("s_waitcnt lgkmcnt(0)" ::: "memory");
    __builtin_amdgcn_sched_barrier(0);
    __builtin_amdgcn_s_barrier();               // plane f free; A(f+1) visible
    __builtin_amdgcn_sched_barrier(0);
  };

#pragma unroll
  for (int ff = 0; ff < F; ff += 2) {
    phase(ff + 0, rA0, rA1);
    phase(ff + 1, rA1, rA0);
  }

  // Epilogue: C/D layout col = lane&15, row = (lane>>4)*4 + reg; bf16 out
  const int ccol = lane & 15;
  const int crow = (lane >> 4) * 4;
  float bv[4];
#pragma unroll
  for (int j = 0; j < 4; j++) bv[j] = bias[n0 + tn + j * 16 + ccol];
#pragma unroll
  for (int i = 0; i < 4; i++) {
#pragma unroll
    for (int j = 0; j < 4; j++) {
      const size_t base =
          (size_t)(m0 + tm + i * 16 + crow) * N + (n0 + tn + j * 16 + ccol);
#pragma unroll
      for (int r = 0; r < 4; r++)
        C[base + (size_t)r * N] = (__bf16)(acc[i][j][r] + bv[j]);
    }
  }
}

// ---------------------------------------------------------------------------
// GEMM1: bf16 A, counted-vmcnt 8ph, 256x256 tile (unchanged from R5 pass).
// ---------------------------------------------------------------------------
__global__ __launch_bounds__(512, 1) void gemm_bt_bias_8ph(
    const __bf16* __restrict__ A,   // [M,K]
    const __bf16* __restrict__ Bm,  // [N,K]
    const float* __restrict__ bias, // [N]
    __bf16* __restrict__ C,         // [M,N]
    int M, int N, int K) {
  __shared__ __bf16 As[2][2][256 * 32];  // 64 KB
  __shared__ __bf16 Bs[2][2][256 * 32];  // 64 KB

  const int tid = threadIdx.x;
  const int lane = tid & 63;
  const int wave = tid >> 6;          // 0..7
  const int wg = xcd_swizzle((int)blockIdx.x, (int)gridDim.x);
  const int nb = N / 256;
  const int bm = wg / nb;
  const int bn = wg % nb;
  const int m0 = bm * 256, n0 = bn * 256;

  floatx4 zero = {0.f, 0.f, 0.f, 0.f};
  floatx4 acc[8][4];
#pragma unroll
  for (int i = 0; i < 8; i++)
#pragma unroll
    for (int j = 0; j < 4; j++) acc[i][j] = zero;

  const int tm = (wave >> 2) * 128;   // 0 / 128
  const int tn = (wave & 3) * 64;     // 0..192
  const int lrow = lane & 15;
  const int sB = lane >> 4;           // 16B-slot 0..3 within a 64B row

  auto S = [&](int t, int c) {
    const int p = t & 1;
    const int k0 = t * 64 + c * 32;
#pragma unroll
    for (int i = 0; i < 2; i++) {
      const int u = wave * 2 + i;        // wave-load index 0..15
      const int e = u * 64 + lane;       // 16B-unit 0..1023
      const int r = e >> 2;              // row 0..255
      const int g = (e & 3) ^ ((r >> 1) & 3);  // pre-swizzled source slot
      async_load16(&A[(size_t)(m0 + r) * K + k0 + g * 8], &As[p][c][u * 512]);
      async_load16(&Bm[(size_t)(n0 + r) * K + k0 + g * 8], &Bs[p][c][u * 512]);
    }
  };

  S(0, 0); S(0, 1); S(1, 0); S(1, 1);

  const int F = (K >> 6) << 1;  // 16 phases for K=512
  for (int f = 0; f < F; ++f) {
    const int t = f >> 1, c = f & 1, p = t & 1;
    if (f >= 1 && f + 3 < F) S((f + 3) >> 1, (f + 3) & 1);

    const int rem = F - 1 - f;
    wait_vm(rem >= 3 ? 12 : rem * 4);   // 12,12,...,12,8,4,0
    __builtin_amdgcn_s_barrier();       // planes of phase f valid block-wide
    __builtin_amdgcn_sched_barrier(0);

    bf16x8 af[8], bfr[4];
#pragma unroll
    for (int i = 0; i < 8; i++) {
      const int ra = tm + i * 16 + lrow;
      af[i] = *(const bf16x8*)&As[p][c][ra * 32 + ((sB ^ ((ra >> 1) & 3)) << 3)];
    }
#pragma unroll
    for (int j = 0; j < 4; j++) {
      const int rb = tn + j * 16 + lrow;
      bfr[j] = *(const bf16x8*)&Bs[p][c][rb * 32 + ((sB ^ ((rb >> 1) & 3)) << 3)];
    }
    __builtin_amdgcn_s_setprio(1);
#pragma unroll
    for (int i = 0; i < 8; i++)
#pragma unroll
      for (int j = 0; j < 4; j++)
        acc[i][j] = __builtin_amdgcn_mfma_f32_16x16x32_bf16(af[i], bfr[j],
                                                            acc[i][j], 0, 0, 0);
    __builtin_amdgcn_s_setprio(0);
    __builtin_amdgcn_sched_barrier(0);
    __builtin_amdgcn_s_barrier();       // all reads of phase-f planes done
    __builtin_amdgcn_sched_barrier(0);
  }

  const int ccol = lane & 15;
  const int crow = (lane >> 4) * 4;
  float bv[4];
#pragma unroll
  for (int j = 0; j < 4; j++) bv[j] = bias[n0 + tn + j * 16 + ccol];
#pragma unroll
  for (int i = 0; i < 8; i++) {
#pragma unroll
    for (int j = 0; j < 4; j++) {
      const size_t base =
          (size_t)(m0 + tm + i * 16 + crow) * N + (n0 + tn + j * 16 + ccol);
#pragma unroll
      for (int r = 0; r < 4; r++)
        C[base + (size_t)r * N] = (__bf16)(acc[i][j][r] + bv[j]);
    }
  }
}

// ---------------------------------------------------------------------------
// IndRNN scan, barrier-free single-wave pipeline (unchanged: 3-deep input
// LDS pipeline, counted vmcnt, batched wide stores).
// ---------------------------------------------------------------------------
#define TS 64
#define NTILE (T_DIM / TS)  // 16

template <bool BF16OUT>
__global__ __launch_bounds__(64, 1) void scan_kernel(
    const __bf16* __restrict__ pre, // [T, BH] bf16
    const float* __restrict__ h0,   // [BH]
    const float* __restrict__ u,    // [H]
    void* __restrict__ outp,        // [T, BH] bf16 or f32
    float* __restrict__ hn) {       // [BH]
  constexpr int OBYTES = BF16OUT ? 2 : 4;
  __shared__ __bf16 tin[3][TS * 64];          // 24 KB, 3-deep input pipeline
  __shared__ char oraw[2][TS * 64 * OBYTES];  // 16/32 KB output staging

  const int lane = threadIdx.x;
  const int c0 = blockIdx.x * 64;
  const int idx = c0 + lane;
  const float uu = u[idx & (H_DIM - 1)];
  float h = h0[idx];

  const int lrow = lane >> 3;      // 0..7
  const int lcg = (lane & 7) * 8;  // 16B chain sub-offset

  // prologue: tiles 0,1 in flight
#pragma unroll
  for (int i = 0; i < 8; i++)
    async_load16(&pre[(size_t)(i * 8 + lrow) * BH + c0 + lcg], &tin[0][i * 512]);
#pragma unroll
  for (int i = 0; i < 8; i++)
    async_load16(&pre[(size_t)(TS + i * 8 + lrow) * BH + c0 + lcg],
                 &tin[1][i * 512]);

  for (int tile = 0; tile < NTILE; ++tile) {
    __builtin_amdgcn_sched_barrier(0);
    if (tile + 2 < NTILE) {
      const int nb = (tile + 2) % 3;
      const size_t nt0 = (size_t)(tile + 2) * TS;
#pragma unroll
      for (int i = 0; i < 8; i++)
        async_load16(&pre[(nt0 + i * 8 + lrow) * BH + c0 + lcg],
                     &tin[nb][i * 512]);
    }
    // exact younger-op counts (loads=8/tile, flush stores=8 or 16/tile)
    int wv;
    if (BF16OUT)
      wv = (tile == 0 || tile == NTILE - 1) ? 16
         : (tile == 1 || tile == NTILE - 2) ? 24 : 32;
    else
      wv = (tile == 0) ? 16
         : (tile == 1 || tile == NTILE - 1) ? 32
         : (tile == NTILE - 2) ? 40 : 48;
    wait_vm(wv);
    __builtin_amdgcn_sched_barrier(0);

    const int buf = tile % 3;
    const int t0 = tile * TS;
    char* ob = oraw[tile & 1];
#pragma unroll
    for (int s = 0; s < TS; s++) {
      const float p = (float)tin[buf][s * 64 + lane];
      h = fmaxf(fmaf(uu, h, p), 0.0f);
      if (BF16OUT) ((__bf16*)ob)[s * 64 + lane] = (__bf16)h;
      else         ((float*)ob)[s * 64 + lane] = h;
    }
    // flush staged tile: wide coalesced stores
    if (BF16OUT) {
#pragma unroll
      for (int i = 0; i < 8; i++) {
        const int row = i * 8 + (lane >> 3);
        const bf16x8 v =
            *(const bf16x8*)&((const __bf16*)ob)[row * 64 + (lane & 7) * 8];
        *(bf16x8*)&((__bf16*)outp)[(size_t)(t0 + row) * BH + c0 + (lane & 7) * 8] = v;
      }
    } else {
#pragma unroll
      for (int i = 0; i < 16; i++) {
        const int row = i * 4 + (lane >> 4);
        const float4 v =
            *(const float4*)&((const float*)ob)[row * 64 + (lane & 15) * 4];
        *(float4*)&((float*)outp)[(size_t)(t0 + row) * BH + c0 + (lane & 15) * 4] = v;
      }
    }
  }
  hn[idx] = h;
}

// ---------------------------------------------------------------------------
extern "C" void kernel_launch(void* const* d_in, const int* in_sizes, int n_in,
                              void* d_out, int out_size, void* d_ws,
                              size_t ws_size, hipStream_t stream) {
  (void)in_sizes; (void)n_in; (void)out_size; (void)ws_size;
  const float* x      = (const float*)d_in[0]; // [T,B,D]
  const float* hidden = (const float*)d_in[1]; // [L,B,H]
  const float* fc_w   = (const float*)d_in[2]; // [D,D]
  const float* fc_b   = (const float*)d_in[3]; // [D]
  const float* w0     = (const float*)d_in[4]; // [H,D]
  const float* b0     = (const float*)d_in[5]; // [H]
  const float* u0     = (const float*)d_in[6]; // [H]
  const float* w1     = (const float*)d_in[7]; // [H,H]
  const float* b1     = (const float*)d_in[8]; // [H]
  const float* u1     = (const float*)d_in[9]; // [H]
  float* out = (float*)d_out;

  // workspace (~129 MB): pre / out0 (bf16, 64 MB each) + small weights
  char* ws = (char*)d_ws;
  __bf16* pre  = (__bf16*)ws;                   // 64 MB
  __bf16* out0 = (__bf16*)(ws + TBH * 2);       // 64 MB
  char*   tail = ws + 2 * TBH * 2;
  __bf16* Wc    = (__bf16*)tail;                // 512 KB
  __bf16* w1bf  = (__bf16*)(tail + 512 * 1024); // 512 KB
  float*  bcomb = (float*)(tail + 1024 * 1024); // 2 KB

  float* hn = out + TBH; // [2, BH] after out1

  // 1) prep: Wc = w0@fc_w (bf16), w1->bf16, bcomb = b0 + w0@fc_b
  prep_kernel<<<258, 256, 0, stream>>>(w0, fc_w, fc_b, b0, w1, Wc, w1bf, bcomb);
  // 2) pre0 = x @ Wc^T + bcomb -> bf16 (f32 A reg-staged, cvt-once, 16 waves)
  gemm_a32_rs<<<(TBROWS / 256) * (H_DIM / 256), 1024, 0, stream>>>(
      x, Wc, bcomb, pre, TBROWS, H_DIM, D_DIM);
  // 3) layer-0 scan: out0 (bf16), hn[0]
  scan_kernel<true><<<BH / 64, 64, 0, stream>>>(pre, hidden, u0, (void*)out0, hn);
  // 4) pre1 = out0 @ w1^T + b1 -> bf16 (counted-vmcnt 8ph)
  gemm_bt_bias_8ph<<<(TBROWS / 256) * (H_DIM / 256), 512, 0, stream>>>(
      out0, w1bf, b1, pre, TBROWS, H_DIM, H_DIM);
  // 5) layer-1 scan: out1 (f32) -> d_out, hn[1]
  scan_kernel<false><<<BH / 64, 64, 0, stream>>>(pre, hidden + BH, u1,
                                                 (void*)out, hn + BH);
}

// Round 9
// 456.655 us; speedup vs baseline: 1.0086x; 1.0086x over previous
//
#include <hip/hip_runtime.h>
#include <hip/hip_bf16.h>
#include <cstdint>
#include <cstddef>

// Problem constants (T,B,D,H,L = 1024,64,512,512,2)
#define T_DIM 1024
#define B_DIM 64
#define D_DIM 512
#define H_DIM 512
#define TBROWS (T_DIM * B_DIM)           // 65536 GEMM rows
#define BH (B_DIM * H_DIM)               // 32768
#define TBH ((size_t)T_DIM * (size_t)BH) // 33554432 elements

typedef __bf16 bf16x8 __attribute__((ext_vector_type(8)));
typedef float floatx4 __attribute__((ext_vector_type(4)));

// ---------------------------------------------------------------------------
// async global->LDS, 16B per lane. LDS dest is wave-uniform base + lane*16.
// ---------------------------------------------------------------------------
__device__ __forceinline__ void async_load16(const void* g, void* l) {
  __builtin_amdgcn_global_load_lds(
      (const __attribute__((address_space(1))) unsigned int*)g,
      (__attribute__((address_space(3))) unsigned int*)l,
      16, 0, 0);
}

// counted vmcnt wait (compile-time literal via switch)
__device__ __forceinline__ void wait_vm(int n) {
  switch (n) {
    case 4:  asm volatile("s_waitcnt vmcnt(4)"  ::: "memory"); break;
    case 6:  asm volatile("s_waitcnt vmcnt(6)"  ::: "memory"); break;
    case 8:  asm volatile("s_waitcnt vmcnt(8)"  ::: "memory"); break;
    case 12: asm volatile("s_waitcnt vmcnt(12)" ::: "memory"); break;
    case 16: asm volatile("s_waitcnt vmcnt(16)" ::: "memory"); break;
    case 20: asm volatile("s_waitcnt vmcnt(20)" ::: "memory"); break;
    case 24: asm volatile("s_waitcnt vmcnt(24)" ::: "memory"); break;
    case 28: asm volatile("s_waitcnt vmcnt(28)" ::: "memory"); break;
    case 32: asm volatile("s_waitcnt vmcnt(32)" ::: "memory"); break;
    case 36: asm volatile("s_waitcnt vmcnt(36)" ::: "memory"); break;
    case 40: asm volatile("s_waitcnt vmcnt(40)" ::: "memory"); break;
    case 44: asm volatile("s_waitcnt vmcnt(44)" ::: "memory"); break;
    case 48: asm volatile("s_waitcnt vmcnt(48)" ::: "memory"); break;
    default: asm volatile("s_waitcnt vmcnt(0)"  ::: "memory"); break;
  }
}

__device__ __forceinline__ int xcd_swizzle(int bid, int nwg) {
  // nwg % 8 == 0 for all launches here -> simple bijective form (m157/m204)
  return (bid & 7) * (nwg >> 3) + (bid >> 3);
}

// ---------------------------------------------------------------------------
// Merged prep:
//   blocks [0,128):    Wc[h,d] = sum_e w0[h,e]*fc_w[e,d] (bf16), 8 h-rows/blk
//   blocks [128,256):  w1 -> bf16
//   blocks [256,258):  bcomb[h] = b0[h] + sum_e w0[h,e]*fc_b[e]
// ---------------------------------------------------------------------------
__global__ __launch_bounds__(256) void prep_kernel(
    const float* __restrict__ w0, const float* __restrict__ fc_w,
    const float* __restrict__ fc_b, const float* __restrict__ b0,
    const float* __restrict__ w1, __bf16* __restrict__ Wc,
    __bf16* __restrict__ w1bf, float* __restrict__ bcomb) {
  const int blk = blockIdx.x;
  const int tid = threadIdx.x;
  if (blk < 128) {
    const int h0 = (blk >> 1) * 8;
    const int d = ((blk & 1) << 8) + tid;
    float a[8];
#pragma unroll
    for (int j = 0; j < 8; j++) a[j] = 0.f;
#pragma unroll 4
    for (int e = 0; e < D_DIM; ++e) {
      const float fv = fc_w[(size_t)e * D_DIM + d];
#pragma unroll
      for (int j = 0; j < 8; j++)
        a[j] = fmaf(w0[(size_t)(h0 + j) * D_DIM + e], fv, a[j]);  // w0: s_load
    }
#pragma unroll
    for (int j = 0; j < 8; j++)
      Wc[(size_t)(h0 + j) * D_DIM + d] = (__bf16)a[j];
  } else if (blk < 256) {
    const long i = ((long)(blk - 128) * 256 + tid) * 8;
    const float4 a = *(const float4*)(w1 + i);
    const float4 b = *(const float4*)(w1 + i + 4);
    bf16x8 v;
    v[0] = (__bf16)a.x; v[1] = (__bf16)a.y; v[2] = (__bf16)a.z; v[3] = (__bf16)a.w;
    v[4] = (__bf16)b.x; v[5] = (__bf16)b.y; v[6] = (__bf16)b.z; v[7] = (__bf16)b.w;
    *(bf16x8*)(w1bf + i) = v;
  } else {
    const int h = (blk - 256) * 256 + tid;
    float acc = b0[h];
    const float4* w4 = (const float4*)(w0 + (size_t)h * D_DIM);
#pragma unroll 4
    for (int e = 0; e < D_DIM / 4; ++e) {
      const float4 wv = w4[e];
      acc = fmaf(wv.x, fc_b[e * 4 + 0], acc);
      acc = fmaf(wv.y, fc_b[e * 4 + 1], acc);
      acc = fmaf(wv.z, fc_b[e * 4 + 2], acc);
      acc = fmaf(wv.w, fc_b[e * 4 + 3], acc);
    }
    bcomb[h] = acc;
  }
}

// ---------------------------------------------------------------------------
// GEMM0: A is f32 (raw x), 256x256 tile, BK=32, ring-of-3 LDS planes,
// counted-vmcnt schedule, 8 waves (2M x 4N -> 128x64/wave), 32 MFMA/phase.
// (R7 kernel, verbatim -- best proven fused-f32A at ~100 us.)
// ---------------------------------------------------------------------------
__global__ __launch_bounds__(512, 1) void gemm_a32_r3(
    const float* __restrict__ A,    // [M,K] f32
    const __bf16* __restrict__ Bm,  // [N,K] bf16
    const float* __restrict__ bias, // [N]
    __bf16* __restrict__ C,         // [M,N] bf16
    int M, int N, int K) {
  __shared__ float Asf[3][256 * 32];   // 96 KB
  __shared__ __bf16 Bs[3][256 * 32];   // 48 KB

  const int tid = threadIdx.x;
  const int lane = tid & 63;
  const int wave = tid >> 6;          // 0..7
  const int wg = xcd_swizzle((int)blockIdx.x, (int)gridDim.x);
  const int nb = N / 256;             // 2
  const int bm = wg / nb;
  const int bn = wg % nb;
  const int m0 = bm * 256, n0 = bn * 256;

  floatx4 zero = {0.f, 0.f, 0.f, 0.f};
  floatx4 acc[8][4];
#pragma unroll
  for (int i = 0; i < 8; i++)
#pragma unroll
    for (int j = 0; j < 4; j++) acc[i][j] = zero;

  const int tm = (wave >> 2) * 128;   // 0 / 128
  const int tn = (wave & 3) * 64;     // 0..192
  const int lrow = lane & 15;
  const int lk = (lane >> 4) * 8;     // k sub-offset 0,8,16,24
  const int sB = lane >> 4;           // bf16 16B-slot 0..3
  const int s0 = lk >> 2;             // f32 16B-slot {0,2,4,6}

  // stage K-tile t (k0 = t*32) into plane pl: 6 loads/wave.
  auto S = [&](int t, int pl) {
    const int k0 = t * 32;
    // A: 256 rows x 128B = 2048 16B-units, 4 per wave-lane
#pragma unroll
    for (int i = 0; i < 4; i++) {
      const int u = wave * 4 + i;            // 0..31
      const int e = u * 64 + lane;
      const int r = e >> 3;                  // 0..255
      const int g = (e & 7) ^ (r & 7);       // pre-swizzled source slot
      async_load16(&A[(size_t)(m0 + r) * K + k0 + g * 4], &Asf[pl][u * 256]);
    }
    // B: 256 rows x 64B = 1024 16B-units, 2 per wave-lane
#pragma unroll
    for (int i = 0; i < 2; i++) {
      const int u = wave * 2 + i;            // 0..15
      const int e = u * 64 + lane;
      const int r = e >> 2;                  // 0..255
      const int g = (e & 3) ^ ((r >> 1) & 3);
      async_load16(&Bm[(size_t)(n0 + r) * K + k0 + g * 8], &Bs[pl][u * 512]);
    }
  };

  // prologue: K-tiles 0,1,2 in flight (18 loads/wave)
  S(0, 0); S(1, 1); S(2, 2);

  const int F = K / 32;  // 16 phases for K=512
  for (int f = 0; f < F; ++f) {
    const int pl = f % 3;
    const int rem = F - 1 - f;
    wait_vm(rem >= 2 ? 12 : (rem == 1 ? 6 : 0));
    __builtin_amdgcn_s_barrier();       // plane pl valid block-wide
    __builtin_amdgcn_sched_barrier(0);

    bf16x8 af[8], bfr[4];
#pragma unroll
    for (int i = 0; i < 8; i++) {
      const int ra = tm + i * 16 + lrow;
      const int k7 = ra & 7;
      const float4 fa = *(const float4*)&Asf[pl][ra * 32 + ((s0 ^ k7) << 2)];
      const float4 fb = *(const float4*)&Asf[pl][ra * 32 + (((s0 + 1) ^ k7) << 2)];
      bf16x8 v;
      v[0] = (__bf16)fa.x; v[1] = (__bf16)fa.y; v[2] = (__bf16)fa.z; v[3] = (__bf16)fa.w;
      v[4] = (__bf16)fb.x; v[5] = (__bf16)fb.y; v[6] = (__bf16)fb.z; v[7] = (__bf16)fb.w;
      af[i] = v;
    }
#pragma unroll
    for (int j = 0; j < 4; j++) {
      const int rb = tn + j * 16 + lrow;
      bfr[j] = *(const bf16x8*)&Bs[pl][rb * 32 + ((sB ^ ((rb >> 1) & 3)) << 3)];
    }
    __builtin_amdgcn_s_setprio(1);
#pragma unroll
    for (int i = 0; i < 8; i++)
#pragma unroll
      for (int j = 0; j < 4; j++)
        acc[i][j] = __builtin_amdgcn_mfma_f32_16x16x32_bf16(af[i], bfr[j],
                                                            acc[i][j], 0, 0, 0);
    __builtin_amdgcn_s_setprio(0);
    __builtin_amdgcn_sched_barrier(0);
    __builtin_amdgcn_s_barrier();       // all reads of plane pl done -> free
    __builtin_amdgcn_sched_barrier(0);
    if (f + 3 < F) S(f + 3, pl);
  }

  const int ccol = lane & 15;
  const int crow = (lane >> 4) * 4;
  float bv[4];
#pragma unroll
  for (int j = 0; j < 4; j++) bv[j] = bias[n0 + tn + j * 16 + ccol];
#pragma unroll
  for (int i = 0; i < 8; i++) {
#pragma unroll
    for (int j = 0; j < 4; j++) {
      const size_t base =
          (size_t)(m0 + tm + i * 16 + crow) * N + (n0 + tn + j * 16 + ccol);
#pragma unroll
      for (int r = 0; r < 4; r++)
        C[base + (size_t)r * N] = (__bf16)(acc[i][j][r] + bv[j]);
    }
  }
}

// ---------------------------------------------------------------------------
// GEMM1: bf16 A, counted-vmcnt 8ph, 256x256 tile (unchanged from R5 pass).
// ---------------------------------------------------------------------------
__global__ __launch_bounds__(512, 1) void gemm_bt_bias_8ph(
    const __bf16* __restrict__ A,   // [M,K]
    const __bf16* __restrict__ Bm,  // [N,K]
    const float* __restrict__ bias, // [N]
    __bf16* __restrict__ C,         // [M,N]
    int M, int N, int K) {
  __shared__ __bf16 As[2][2][256 * 32];  // 64 KB
  __shared__ __bf16 Bs[2][2][256 * 32];  // 64 KB

  const int tid = threadIdx.x;
  const int lane = tid & 63;
  const int wave = tid >> 6;          // 0..7
  const int wg = xcd_swizzle((int)blockIdx.x, (int)gridDim.x);
  const int nb = N / 256;
  const int bm = wg / nb;
  const int bn = wg % nb;
  const int m0 = bm * 256, n0 = bn * 256;

  floatx4 zero = {0.f, 0.f, 0.f, 0.f};
  floatx4 acc[8][4];
#pragma unroll
  for (int i = 0; i < 8; i++)
#pragma unroll
    for (int j = 0; j < 4; j++) acc[i][j] = zero;

  const int tm = (wave >> 2) * 128;   // 0 / 128
  const int tn = (wave & 3) * 64;     // 0..192
  const int lrow = lane & 15;
  const int sB = lane >> 4;           // 16B-slot 0..3 within a 64B row

  auto S = [&](int t, int c) {
    const int p = t & 1;
    const int k0 = t * 64 + c * 32;
#pragma unroll
    for (int i = 0; i < 2; i++) {
      const int u = wave * 2 + i;        // wave-load index 0..15
      const int e = u * 64 + lane;       // 16B-unit 0..1023
      const int r = e >> 2;              // row 0..255
      const int g = (e & 3) ^ ((r >> 1) & 3);  // pre-swizzled source slot
      async_load16(&A[(size_t)(m0 + r) * K + k0 + g * 8], &As[p][c][u * 512]);
      async_load16(&Bm[(size_t)(n0 + r) * K + k0 + g * 8], &Bs[p][c][u * 512]);
    }
  };

  S(0, 0); S(0, 1); S(1, 0); S(1, 1);

  const int F = (K >> 6) << 1;  // 16 phases for K=512
  for (int f = 0; f < F; ++f) {
    const int t = f >> 1, c = f & 1, p = t & 1;
    if (f >= 1 && f + 3 < F) S((f + 3) >> 1, (f + 3) & 1);

    const int rem = F - 1 - f;
    wait_vm(rem >= 3 ? 12 : rem * 4);   // 12,12,...,12,8,4,0
    __builtin_amdgcn_s_barrier();       // planes of phase f valid block-wide
    __builtin_amdgcn_sched_barrier(0);

    bf16x8 af[8], bfr[4];
#pragma unroll
    for (int i = 0; i < 8; i++) {
      const int ra = tm + i * 16 + lrow;
      af[i] = *(const bf16x8*)&As[p][c][ra * 32 + ((sB ^ ((ra >> 1) & 3)) << 3)];
    }
#pragma unroll
    for (int j = 0; j < 4; j++) {
      const int rb = tn + j * 16 + lrow;
      bfr[j] = *(const bf16x8*)&Bs[p][c][rb * 32 + ((sB ^ ((rb >> 1) & 3)) << 3)];
    }
    __builtin_amdgcn_s_setprio(1);
#pragma unroll
    for (int i = 0; i < 8; i++)
#pragma unroll
      for (int j = 0; j < 4; j++)
        acc[i][j] = __builtin_amdgcn_mfma_f32_16x16x32_bf16(af[i], bfr[j],
                                                            acc[i][j], 0, 0, 0);
    __builtin_amdgcn_s_setprio(0);
    __builtin_amdgcn_sched_barrier(0);
    __builtin_amdgcn_s_barrier();       // all reads of phase-f planes done
    __builtin_amdgcn_sched_barrier(0);
  }

  const int ccol = lane & 15;
  const int crow = (lane >> 4) * 4;
  float bv[4];
#pragma unroll
  for (int j = 0; j < 4; j++) bv[j] = bias[n0 + tn + j * 16 + ccol];
#pragma unroll
  for (int i = 0; i < 8; i++) {
#pragma unroll
    for (int j = 0; j < 4; j++) {
      const size_t base =
          (size_t)(m0 + tm + i * 16 + crow) * N + (n0 + tn + j * 16 + ccol);
#pragma unroll
      for (int r = 0; r < 4; r++)
        C[base + (size_t)r * N] = (__bf16)(acc[i][j][r] + bv[j]);
    }
  }
}

// ---------------------------------------------------------------------------
// IndRNN scan v2: deeper latency hiding. TS=32 tiles (4 loads + 4/8 stores
// per tile) -> depth-4 prefetch fits the 6-bit vmcnt ledger for BOTH output
// dtypes: steady younger-ops = 4 load-groups (16) + 4 store-groups
// (16 bf16 / 32 f32) = 32 / 48 <= 63. Ring-6 input LDS (24 KB); horizon
// ~4 tiles (~1.3 us of compute) >= HBM-under-load latency, so the per-tile
// wait_vm should retire without stalling. No vmcnt(0) until the last tile.
// Exact ledger: wv(t) = 4*min(4, NT-1-t) + S_s*min(4, t), S_s = 4 bf16 /
// 8 f32 (audited: vmem issue order ... l(t), s(t-4), l(t+1), s(t-3), l(t+2),
// s(t-2), l(t+3), s(t-1), l(t+4), WAIT).
// ---------------------------------------------------------------------------
#define TS2 32
#define NT2 (T_DIM / TS2)  // 32

template <bool BF16OUT>
__global__ __launch_bounds__(64, 1) void scan_kernel(
    const __bf16* __restrict__ pre, // [T, BH] bf16
    const float* __restrict__ h0,   // [BH]
    const float* __restrict__ u,    // [H]
    void* __restrict__ outp,        // [T, BH] bf16 or f32
    float* __restrict__ hn) {       // [BH]
  constexpr int OBYTES = BF16OUT ? 2 : 4;
  constexpr int SS = BF16OUT ? 4 : 8;          // flush stores per tile
  __shared__ __bf16 tin[6][TS2 * 64];          // 6 x 4 KB input ring
  __shared__ char oraw[2][TS2 * 64 * OBYTES];  // 8 / 16 KB output staging

  const int lane = threadIdx.x;
  const int c0 = blockIdx.x * 64;
  const int idx = c0 + lane;
  const float uu = u[idx & (H_DIM - 1)];
  float h = h0[idx];

  const int lrow = lane >> 3;      // 0..7
  const int lcg = (lane & 7) * 8;  // 16B chain sub-offset

  // issue the 4 loads of tile t into ring slot t%6
  auto issueL = [&](int t) {
    const size_t r0 = (size_t)t * TS2;
#pragma unroll
    for (int i = 0; i < 4; i++)
      async_load16(&pre[(r0 + i * 8 + lrow) * BH + c0 + lcg],
                   &tin[t % 6][i * 512]);
  };

  // prologue: tiles 0..3 in flight (16 loads)
  issueL(0); issueL(1); issueL(2); issueL(3);

  for (int tile = 0; tile < NT2; ++tile) {
    __builtin_amdgcn_sched_barrier(0);
    if (tile + 4 < NT2) issueL(tile + 4);
    // exact younger-op count for loads(tile)
    const int fl = NT2 - 1 - tile;
    const int wv = 4 * (fl < 4 ? fl : 4) + SS * (tile < 4 ? tile : 4);
    wait_vm(wv);
    __builtin_amdgcn_sched_barrier(0);

    const int buf = tile % 6;
    const int t0 = tile * TS2;
    char* ob = oraw[tile & 1];
#pragma unroll
    for (int s = 0; s < TS2; s++) {
      const float p = (float)tin[buf][s * 64 + lane];
      h = fmaxf(fmaf(uu, h, p), 0.0f);
      if (BF16OUT) ((__bf16*)ob)[s * 64 + lane] = (__bf16)h;
      else         ((float*)ob)[s * 64 + lane] = h;
    }
    // flush staged tile: wide coalesced stores (4 bf16 / 8 f32 dwordx4)
    if (BF16OUT) {
#pragma unroll
      for (int i = 0; i < 4; i++) {
        const int row = i * 8 + (lane >> 3);
        const bf16x8 v =
            *(const bf16x8*)&((const __bf16*)ob)[row * 64 + (lane & 7) * 8];
        *(bf16x8*)&((__bf16*)outp)[(size_t)(t0 + row) * BH + c0 + (lane & 7) * 8] = v;
      }
    } else {
#pragma unroll
      for (int i = 0; i < 8; i++) {
        const int row = i * 4 + (lane >> 4);
        const float4 v =
            *(const float4*)&((const float*)ob)[row * 64 + (lane & 15) * 4];
        *(float4*)&((float*)outp)[(size_t)(t0 + row) * BH + c0 + (lane & 15) * 4] = v;
      }
    }
  }
  hn[idx] = h;
}

// ---------------------------------------------------------------------------
extern "C" void kernel_launch(void* const* d_in, const int* in_sizes, int n_in,
                              void* d_out, int out_size, void* d_ws,
                              size_t ws_size, hipStream_t stream) {
  (void)in_sizes; (void)n_in; (void)out_size; (void)ws_size;
  const float* x      = (const float*)d_in[0]; // [T,B,D]
  const float* hidden = (const float*)d_in[1]; // [L,B,H]
  const float* fc_w   = (const float*)d_in[2]; // [D,D]
  const float* fc_b   = (const float*)d_in[3]; // [D]
  const float* w0     = (const float*)d_in[4]; // [H,D]
  const float* b0     = (const float*)d_in[5]; // [H]
  const float* u0     = (const float*)d_in[6]; // [H]
  const float* w1     = (const float*)d_in[7]; // [H,H]
  const float* b1     = (const float*)d_in[8]; // [H]
  const float* u1     = (const float*)d_in[9]; // [H]
  float* out = (float*)d_out;

  // workspace (~129 MB): pre / out0 (bf16, 64 MB each) + small weights
  char* ws = (char*)d_ws;
  __bf16* pre  = (__bf16*)ws;                   // 64 MB
  __bf16* out0 = (__bf16*)(ws + TBH * 2);       // 64 MB
  char*   tail = ws + 2 * TBH * 2;
  __bf16* Wc    = (__bf16*)tail;                // 512 KB
  __bf16* w1bf  = (__bf16*)(tail + 512 * 1024); // 512 KB
  float*  bcomb = (float*)(tail + 1024 * 1024); // 2 KB

  float* hn = out + TBH; // [2, BH] after out1

  // 1) prep: Wc = w0@fc_w (bf16), w1->bf16, bcomb = b0 + w0@fc_b
  prep_kernel<<<258, 256, 0, stream>>>(w0, fc_w, fc_b, b0, w1, Wc, w1bf, bcomb);
  // 2) pre0 = x @ Wc^T + bcomb -> bf16 (f32 A, ring-3 counted-vmcnt, no cvt)
  gemm_a32_r3<<<(TBROWS / 256) * (H_DIM / 256), 512, 0, stream>>>(
      x, Wc, bcomb, pre, TBROWS, H_DIM, D_DIM);
  // 3) layer-0 scan: out0 (bf16), hn[0]
  scan_kernel<true><<<BH / 64, 64, 0, stream>>>(pre, hidden, u0, (void*)out0, hn);
  // 4) pre1 = out0 @ w1^T + b1 -> bf16 (counted-vmcnt 8ph)
  gemm_bt_bias_8ph<<<(TBROWS / 256) * (H_DIM / 256), 512, 0, stream>>>(
      out0, w1bf, b1, pre, TBROWS, H_DIM, H_DIM);
  // 5) layer-1 scan: out1 (f32) -> d_out, hn[1]
  scan_kernel<false><<<BH / 64, 64, 0, stream>>>(pre, hidden + BH, u1,
                                                 (void*)out, hn + BH);
}

// Round 10
// 447.745 us; speedup vs baseline: 1.0287x; 1.0199x over previous
//
#include <hip/hip_runtime.h>
#include <hip/hip_bf16.h>
#include <cstdint>
#include <cstddef>

// Problem constants (T,B,D,H,L = 1024,64,512,512,2)
#define T_DIM 1024
#define B_DIM 64
#define D_DIM 512
#define H_DIM 512
#define TBROWS (T_DIM * B_DIM)           // 65536 GEMM rows
#define BH (B_DIM * H_DIM)               // 32768
#define TBH ((size_t)T_DIM * (size_t)BH) // 33554432 elements

typedef __bf16 bf16x8 __attribute__((ext_vector_type(8)));
typedef float floatx4 __attribute__((ext_vector_type(4)));

#define BM 256
#define BN 256
#define BK 32

// ---------------------------------------------------------------------------
// async global->LDS, 16B per lane. LDS dest is wave-uniform base + lane*16.
// ---------------------------------------------------------------------------
__device__ __forceinline__ void async_load16(const void* g, void* l) {
  __builtin_amdgcn_global_load_lds(
      (const __attribute__((address_space(1))) unsigned int*)g,
      (__attribute__((address_space(3))) unsigned int*)l,
      16, 0, 0);
}

// counted vmcnt wait (compile-time literal via switch)
__device__ __forceinline__ void wait_vm(int n) {
  switch (n) {
    case 4:  asm volatile("s_waitcnt vmcnt(4)"  ::: "memory"); break;
    case 8:  asm volatile("s_waitcnt vmcnt(8)"  ::: "memory"); break;
    case 12: asm volatile("s_waitcnt vmcnt(12)" ::: "memory"); break;
    case 16: asm volatile("s_waitcnt vmcnt(16)" ::: "memory"); break;
    case 24: asm volatile("s_waitcnt vmcnt(24)" ::: "memory"); break;
    case 32: asm volatile("s_waitcnt vmcnt(32)" ::: "memory"); break;
    case 40: asm volatile("s_waitcnt vmcnt(40)" ::: "memory"); break;
    case 48: asm volatile("s_waitcnt vmcnt(48)" ::: "memory"); break;
    default: asm volatile("s_waitcnt vmcnt(0)"  ::: "memory"); break;
  }
}

__device__ __forceinline__ int xcd_swizzle(int bid, int nwg) {
  // nwg % 8 == 0 for all launches here -> simple bijective form (m157/m204)
  return (bid & 7) * (nwg >> 3) + (bid >> 3);
}

// ---------------------------------------------------------------------------
// Merged prep:
//   blocks [0,128):    Wc[h,d] = sum_e w0[h,e]*fc_w[e,d] (bf16), 8 h-rows/blk
//   blocks [128,256):  w1 -> bf16
//   blocks [256,258):  bcomb[h] = b0[h] + sum_e w0[h,e]*fc_b[e]
// ---------------------------------------------------------------------------
__global__ __launch_bounds__(256) void prep_kernel(
    const float* __restrict__ w0, const float* __restrict__ fc_w,
    const float* __restrict__ fc_b, const float* __restrict__ b0,
    const float* __restrict__ w1, __bf16* __restrict__ Wc,
    __bf16* __restrict__ w1bf, float* __restrict__ bcomb) {
  const int blk = blockIdx.x;
  const int tid = threadIdx.x;
  if (blk < 128) {
    const int h0 = (blk >> 1) * 8;
    const int d = ((blk & 1) << 8) + tid;
    float a[8];
#pragma unroll
    for (int j = 0; j < 8; j++) a[j] = 0.f;
#pragma unroll 4
    for (int e = 0; e < D_DIM; ++e) {
      const float fv = fc_w[(size_t)e * D_DIM + d];
#pragma unroll
      for (int j = 0; j < 8; j++)
        a[j] = fmaf(w0[(size_t)(h0 + j) * D_DIM + e], fv, a[j]);  // w0: s_load
    }
#pragma unroll
    for (int j = 0; j < 8; j++)
      Wc[(size_t)(h0 + j) * D_DIM + d] = (__bf16)a[j];
  } else if (blk < 256) {
    const long i = ((long)(blk - 128) * 256 + tid) * 8;
    const float4 a = *(const float4*)(w1 + i);
    const float4 b = *(const float4*)(w1 + i + 4);
    bf16x8 v;
    v[0] = (__bf16)a.x; v[1] = (__bf16)a.y; v[2] = (__bf16)a.z; v[3] = (__bf16)a.w;
    v[4] = (__bf16)b.x; v[5] = (__bf16)b.y; v[6] = (__bf16)b.z; v[7] = (__bf16)b.w;
    *(bf16x8*)(w1bf + i) = v;
  } else {
    const int h = (blk - 256) * 256 + tid;
    float acc = b0[h];
    const float4* w4 = (const float4*)(w0 + (size_t)h * D_DIM);
#pragma unroll 4
    for (int e = 0; e < D_DIM / 4; ++e) {
      const float4 wv = w4[e];
      acc = fmaf(wv.x, fc_b[e * 4 + 0], acc);
      acc = fmaf(wv.y, fc_b[e * 4 + 1], acc);
      acc = fmaf(wv.z, fc_b[e * 4 + 2], acc);
      acc = fmaf(wv.w, fc_b[e * 4 + 3], acc);
    }
    bcomb[h] = acc;
  }
}

// ---------------------------------------------------------------------------
// GEMM0: A is f32 (raw x), 256x256 tile, BK=32, dbuf 2-phase (R4 verbatim --
// best measured fused-f32A at 96 us). Prefetch issued BEFORE compute, one
// __syncthreads per K-step (its vmcnt(0) drains behind the 32-MFMA block).
// f32 A swizzle: source slot (e&7)^(row&7), read slot s0^(row&7).
// bf16 B swizzle: source slot (e&3)^((row>>1)&3), read slot sB^((row>>1)&3).
// ---------------------------------------------------------------------------
__global__ __launch_bounds__(512, 1) void gemm_a32_bt_bias(
    const float* __restrict__ A,    // [M,K] f32
    const __bf16* __restrict__ Bm,  // [N,K] bf16
    const float* __restrict__ bias, // [N]
    __bf16* __restrict__ C,         // [M,N] bf16
    int M, int N, int K) {
  __shared__ float Asf[2][BM * BK];   // 2 x 32 KB
  __shared__ __bf16 Bs[2][BN * BK];   // 2 x 16 KB   (96 KB total)

  const int tid = threadIdx.x;
  const int lane = tid & 63;
  const int wave = tid >> 6;          // 0..7
  const int wg = xcd_swizzle((int)blockIdx.x, (int)gridDim.x);
  const int nb = N / BN;              // 2
  const int bm = wg / nb;
  const int bn = wg % nb;
  const int m0 = bm * BM, n0 = bn * BN;

  floatx4 zero = {0.f, 0.f, 0.f, 0.f};
  floatx4 acc[8][4];
#pragma unroll
  for (int i = 0; i < 8; i++)
#pragma unroll
    for (int j = 0; j < 4; j++) acc[i][j] = zero;

  const int tm = (wave >> 2) * 128;   // 0 / 128
  const int tn = (wave & 3) * 64;     // 0..192
  const int lrow = lane & 15;
  const int lk = (lane >> 4) * 8;
  const int sB = lk >> 3;             // bf16 16B-slot index 0..3
  const int s0 = lk >> 2;             // f32 16B-slot index {0,2,4,6}

  const int KT = K / BK;              // 16

  // ---- stage K-tile at k0 into buffer b (6 loads per wave) ----
  auto stage = [&](int b, int k0) {
    // A: 256 rows x 128B = 2048 16B-units; 4 per wave-lane
#pragma unroll
    for (int i = 0; i < 4; i++) {
      const int e = (wave * 4 + i) * 64 + lane;
      const int r = e >> 3;                    // 0..255
      const int g = (e & 7) ^ (r & 7);         // pre-swizzled source slot
      async_load16(&A[(size_t)(m0 + r) * K + k0 + g * 4],
                   &Asf[b][(wave * 4 + i) * 256]);
    }
    // B: 256 rows x 64B = 1024 16B-units; 2 per wave-lane
#pragma unroll
    for (int i = 0; i < 2; i++) {
      const int e = (wave * 2 + i) * 64 + lane;
      const int r = e >> 2;                    // 0..255
      const int g = (e & 3) ^ ((r >> 1) & 3);
      async_load16(&Bm[(size_t)(n0 + r) * K + k0 + g * 8],
                   &Bs[b][(wave * 2 + i) * 512]);
    }
  };

  stage(0, 0);
  __syncthreads();

  int cur = 0;
  for (int kt = 0; kt < KT; ++kt) {
    if (kt + 1 < KT) stage(cur ^ 1, (kt + 1) * BK);

    bf16x8 af[8], bfr[4];
#pragma unroll
    for (int i = 0; i < 8; i++) {
      const int ra = tm + i * 16 + lrow;
      const int k7 = ra & 7;
      const float4 fa = *(const float4*)&Asf[cur][ra * 32 + ((s0 ^ k7) << 2)];
      const float4 fb = *(const float4*)&Asf[cur][ra * 32 + (((s0 + 1) ^ k7) << 2)];
      bf16x8 v;
      v[0] = (__bf16)fa.x; v[1] = (__bf16)fa.y; v[2] = (__bf16)fa.z; v[3] = (__bf16)fa.w;
      v[4] = (__bf16)fb.x; v[5] = (__bf16)fb.y; v[6] = (__bf16)fb.z; v[7] = (__bf16)fb.w;
      af[i] = v;
    }
#pragma unroll
    for (int j = 0; j < 4; j++) {
      const int rb = tn + j * 16 + lrow;
      bfr[j] = *(const bf16x8*)&Bs[cur][rb * 32 + ((sB ^ ((rb >> 1) & 3)) << 3)];
    }
#pragma unroll
    for (int i = 0; i < 8; i++)
#pragma unroll
      for (int j = 0; j < 4; j++)
        acc[i][j] = __builtin_amdgcn_mfma_f32_16x16x32_bf16(af[i], bfr[j],
                                                            acc[i][j], 0, 0, 0);
    __syncthreads();  // drains this wave's prefetch; compute hid the latency
    cur ^= 1;
  }

  const int ccol = lane & 15;
  const int crow = (lane >> 4) * 4;
  float bv[4];
#pragma unroll
  for (int j = 0; j < 4; j++) bv[j] = bias[n0 + tn + j * 16 + ccol];
#pragma unroll
  for (int i = 0; i < 8; i++) {
#pragma unroll
    for (int j = 0; j < 4; j++) {
      const size_t base =
          (size_t)(m0 + tm + i * 16 + crow) * N + (n0 + tn + j * 16 + ccol);
#pragma unroll
      for (int r = 0; r < 4; r++)
        C[base + (size_t)r * N] = (__bf16)(acc[i][j][r] + bv[j]);
    }
  }
}

// ---------------------------------------------------------------------------
// GEMM1: bf16 A, counted-vmcnt 8ph, 256x256 tile (unchanged from R5 pass).
// ---------------------------------------------------------------------------
__global__ __launch_bounds__(512, 1) void gemm_bt_bias_8ph(
    const __bf16* __restrict__ A,   // [M,K]
    const __bf16* __restrict__ Bm,  // [N,K]
    const float* __restrict__ bias, // [N]
    __bf16* __restrict__ C,         // [M,N]
    int M, int N, int K) {
  __shared__ __bf16 As[2][2][256 * 32];  // 64 KB
  __shared__ __bf16 Bs[2][2][256 * 32];  // 64 KB

  const int tid = threadIdx.x;
  const int lane = tid & 63;
  const int wave = tid >> 6;          // 0..7
  const int wg = xcd_swizzle((int)blockIdx.x, (int)gridDim.x);
  const int nb = N / 256;
  const int bm = wg / nb;
  const int bn = wg % nb;
  const int m0 = bm * 256, n0 = bn * 256;

  floatx4 zero = {0.f, 0.f, 0.f, 0.f};
  floatx4 acc[8][4];
#pragma unroll
  for (int i = 0; i < 8; i++)
#pragma unroll
    for (int j = 0; j < 4; j++) acc[i][j] = zero;

  const int tm = (wave >> 2) * 128;   // 0 / 128
  const int tn = (wave & 3) * 64;     // 0..192
  const int lrow = lane & 15;
  const int sB = lane >> 4;           // 16B-slot 0..3 within a 64B row

  auto S = [&](int t, int c) {
    const int p = t & 1;
    const int k0 = t * 64 + c * 32;
#pragma unroll
    for (int i = 0; i < 2; i++) {
      const int u = wave * 2 + i;        // wave-load index 0..15
      const int e = u * 64 + lane;       // 16B-unit 0..1023
      const int r = e >> 2;              // row 0..255
      const int g = (e & 3) ^ ((r >> 1) & 3);  // pre-swizzled source slot
      async_load16(&A[(size_t)(m0 + r) * K + k0 + g * 8], &As[p][c][u * 512]);
      async_load16(&Bm[(size_t)(n0 + r) * K + k0 + g * 8], &Bs[p][c][u * 512]);
    }
  };

  S(0, 0); S(0, 1); S(1, 0); S(1, 1);

  const int F = (K >> 6) << 1;  // 16 phases for K=512
  for (int f = 0; f < F; ++f) {
    const int t = f >> 1, c = f & 1, p = t & 1;
    if (f >= 1 && f + 3 < F) S((f + 3) >> 1, (f + 3) & 1);

    const int rem = F - 1 - f;
    wait_vm(rem >= 3 ? 12 : rem * 4);   // 12,12,...,12,8,4,0
    __builtin_amdgcn_s_barrier();       // planes of phase f valid block-wide
    __builtin_amdgcn_sched_barrier(0);

    bf16x8 af[8], bfr[4];
#pragma unroll
    for (int i = 0; i < 8; i++) {
      const int ra = tm + i * 16 + lrow;
      af[i] = *(const bf16x8*)&As[p][c][ra * 32 + ((sB ^ ((ra >> 1) & 3)) << 3)];
    }
#pragma unroll
    for (int j = 0; j < 4; j++) {
      const int rb = tn + j * 16 + lrow;
      bfr[j] = *(const bf16x8*)&Bs[p][c][rb * 32 + ((sB ^ ((rb >> 1) & 3)) << 3)];
    }
    __builtin_amdgcn_s_setprio(1);
#pragma unroll
    for (int i = 0; i < 8; i++)
#pragma unroll
      for (int j = 0; j < 4; j++)
        acc[i][j] = __builtin_amdgcn_mfma_f32_16x16x32_bf16(af[i], bfr[j],
                                                            acc[i][j], 0, 0, 0);
    __builtin_amdgcn_s_setprio(0);
    __builtin_amdgcn_sched_barrier(0);
    __builtin_amdgcn_s_barrier();       // all reads of phase-f planes done
    __builtin_amdgcn_sched_barrier(0);
  }

  const int ccol = lane & 15;
  const int crow = (lane >> 4) * 4;
  float bv[4];
#pragma unroll
  for (int j = 0; j < 4; j++) bv[j] = bias[n0 + tn + j * 16 + ccol];
#pragma unroll
  for (int i = 0; i < 8; i++) {
#pragma unroll
    for (int j = 0; j < 4; j++) {
      const size_t base =
          (size_t)(m0 + tm + i * 16 + crow) * N + (n0 + tn + j * 16 + ccol);
#pragma unroll
      for (int r = 0; r < 4; r++)
        C[base + (size_t)r * N] = (__bf16)(acc[i][j][r] + bv[j]);
    }
  }
}

// ---------------------------------------------------------------------------
// IndRNN scan v3: R7 TS=64 structure, depth templated by dtype.
//   bf16 out: D=3 (ring-4, 24 KB in flight; ledger 8*3+8*3 = 48 <= 63)
//   f32 out:  D=2 (ring-3, ledger-capped: 8*2+16*2 = 48; formula reproduces
//             R7's exact waits 16/32/40/48/32)
// wv(t) = 8*min(D, NT-1-t) + SS*min(D, t)  [exact younger-op count at the
// wait for tile t's loads; in-order vmem retirement makes it precise]
// ---------------------------------------------------------------------------
#define TS 64
#define NTS (T_DIM / TS)  // 16

template <bool BF16OUT>
__global__ __launch_bounds__(64, 1) void scan_kernel(
    const __bf16* __restrict__ pre, // [T, BH] bf16
    const float* __restrict__ h0,   // [BH]
    const float* __restrict__ u,    // [H]
    void* __restrict__ outp,        // [T, BH] bf16 or f32
    float* __restrict__ hn) {       // [BH]
  constexpr int OBYTES = BF16OUT ? 2 : 4;
  constexpr int D = BF16OUT ? 3 : 2;           // prefetch depth (tiles)
  constexpr int R = D + 1;                     // input ring size
  constexpr int SS = BF16OUT ? 8 : 16;         // flush stores per tile
  __shared__ __bf16 tin[R][TS * 64];           // 32 / 24 KB input ring
  __shared__ char oraw[2][TS * 64 * OBYTES];   // 16 / 32 KB output staging

  const int lane = threadIdx.x;
  const int c0 = blockIdx.x * 64;
  const int idx = c0 + lane;
  const float uu = u[idx & (H_DIM - 1)];
  float h = h0[idx];

  const int lrow = lane >> 3;      // 0..7
  const int lcg = (lane & 7) * 8;  // 16B chain sub-offset

  // issue the 8 loads of tile t into ring slot t%R
  auto issueL = [&](int t) {
    const size_t r0 = (size_t)t * TS;
#pragma unroll
    for (int i = 0; i < 8; i++)
      async_load16(&pre[(r0 + i * 8 + lrow) * BH + c0 + lcg],
                   &tin[t % R][i * 512]);
  };

#pragma unroll
  for (int t = 0; t < D; ++t) issueL(t);

  for (int tile = 0; tile < NTS; ++tile) {
    __builtin_amdgcn_sched_barrier(0);
    if (tile + D < NTS) issueL(tile + D);
    const int fl = NTS - 1 - tile;
    const int wv = 8 * (fl < D ? fl : D) + SS * (tile < D ? tile : D);
    wait_vm(wv);
    __builtin_amdgcn_sched_barrier(0);

    const int buf = tile % R;
    const int t0 = tile * TS;
    char* ob = oraw[tile & 1];
#pragma unroll
    for (int s = 0; s < TS; s++) {
      const float p = (float)tin[buf][s * 64 + lane];
      h = fmaxf(fmaf(uu, h, p), 0.0f);
      if (BF16OUT) ((__bf16*)ob)[s * 64 + lane] = (__bf16)h;
      else         ((float*)ob)[s * 64 + lane] = h;
    }
    // flush staged tile: wide coalesced stores (8 bf16 / 16 f32 dwordx4)
    if (BF16OUT) {
#pragma unroll
      for (int i = 0; i < 8; i++) {
        const int row = i * 8 + (lane >> 3);
        const bf16x8 v =
            *(const bf16x8*)&((const __bf16*)ob)[row * 64 + (lane & 7) * 8];
        *(bf16x8*)&((__bf16*)outp)[(size_t)(t0 + row) * BH + c0 + (lane & 7) * 8] = v;
      }
    } else {
#pragma unroll
      for (int i = 0; i < 16; i++) {
        const int row = i * 4 + (lane >> 4);
        const float4 v =
            *(const float4*)&((const float*)ob)[row * 64 + (lane & 15) * 4];
        *(float4*)&((float*)outp)[(size_t)(t0 + row) * BH + c0 + (lane & 15) * 4] = v;
      }
    }
  }
  hn[idx] = h;
}

// ---------------------------------------------------------------------------
extern "C" void kernel_launch(void* const* d_in, const int* in_sizes, int n_in,
                              void* d_out, int out_size, void* d_ws,
                              size_t ws_size, hipStream_t stream) {
  (void)in_sizes; (void)n_in; (void)out_size; (void)ws_size;
  const float* x      = (const float*)d_in[0]; // [T,B,D]
  const float* hidden = (const float*)d_in[1]; // [L,B,H]
  const float* fc_w   = (const float*)d_in[2]; // [D,D]
  const float* fc_b   = (const float*)d_in[3]; // [D]
  const float* w0     = (const float*)d_in[4]; // [H,D]
  const float* b0     = (const float*)d_in[5]; // [H]
  const float* u0     = (const float*)d_in[6]; // [H]
  const float* w1     = (const float*)d_in[7]; // [H,H]
  const float* b1     = (const float*)d_in[8]; // [H]
  const float* u1     = (const float*)d_in[9]; // [H]
  float* out = (float*)d_out;

  // workspace (~129 MB): pre / out0 (bf16, 64 MB each) + small weights
  char* ws = (char*)d_ws;
  __bf16* pre  = (__bf16*)ws;                   // 64 MB
  __bf16* out0 = (__bf16*)(ws + TBH * 2);       // 64 MB
  char*   tail = ws + 2 * TBH * 2;
  __bf16* Wc    = (__bf16*)tail;                // 512 KB
  __bf16* w1bf  = (__bf16*)(tail + 512 * 1024); // 512 KB
  float*  bcomb = (float*)(tail + 1024 * 1024); // 2 KB

  float* hn = out + TBH; // [2, BH] after out1

  // 1) prep: Wc = w0@fc_w (bf16), w1->bf16, bcomb = b0 + w0@fc_b
  prep_kernel<<<258, 256, 0, stream>>>(w0, fc_w, fc_b, b0, w1, Wc, w1bf, bcomb);
  // 2) pre0 = x @ Wc^T + bcomb -> bf16 (R4 2-phase fused-f32A, 96 us proven)
  gemm_a32_bt_bias<<<(TBROWS / BM) * (H_DIM / BN), 512, 0, stream>>>(
      x, Wc, bcomb, pre, TBROWS, H_DIM, D_DIM);
  // 3) layer-0 scan: out0 (bf16), hn[0]
  scan_kernel<true><<<BH / 64, 64, 0, stream>>>(pre, hidden, u0, (void*)out0, hn);
  // 4) pre1 = out0 @ w1^T + b1 -> bf16 (counted-vmcnt 8ph)
  gemm_bt_bias_8ph<<<(TBROWS / 256) * (H_DIM / 256), 512, 0, stream>>>(
      out0, w1bf, b1, pre, TBROWS, H_DIM, H_DIM);
  // 5) layer-1 scan: out1 (f32) -> d_out, hn[1]
  scan_kernel<false><<<BH / 64, 64, 0, stream>>>(pre, hidden + BH, u1,
                                                 (void*)out, hn + BH);
}